// Round 1
// baseline (1667.448 us; speedup 1.0000x reference)
//
#include <hip/hip_runtime.h>
#include <hip/hip_bf16.h>
#include <stdint.h>

// SelfAttLogn: B=8 T=2048 DM=1024 H=16 DH=64, LOG_LEN=11
// Stages: convert->bf16 | QKV gemm (MFMA bf16) | per-level spans | merge softmax | out gemm

typedef unsigned short u16;
typedef __attribute__((ext_vector_type(8))) short bf16x8;
typedef __attribute__((ext_vector_type(4))) float f32x4;

#define B_ 8
#define T_ 2048
#define H_ 16
#define DHD 64
#define LOGL 11

__device__ __forceinline__ float b2f(u16 u){
  union { float f; unsigned int i; } x; x.i = ((unsigned int)u) << 16; return x.f;
}
__device__ __forceinline__ u16 f2b(float f){
  union { float f; unsigned int i; } x; x.f = f;
  unsigned int r = x.i + 0x7fffu + ((x.i >> 16) & 1u);
  return (u16)(r >> 16);
}
__device__ __forceinline__ float wave_sum(float v){
  #pragma unroll
  for (int o = 32; o > 0; o >>= 1) v += __shfl_xor(v, o);
  return v;
}

// ---------------- convert inputs to bf16 ----------------
// xb: [16384][1024]; wqkvb: [1024][3072] (wq|wk|wv cols); wob: [1024][1024]
__global__ __launch_bounds__(256) void convert_kernel(
    const float* __restrict__ x, const float* __restrict__ wq,
    const float* __restrict__ wk, const float* __restrict__ wv,
    const float* __restrict__ wo,
    u16* __restrict__ xb, u16* __restrict__ wqkvb, u16* __restrict__ wob)
{
  const size_t NX = 16777216ull;      // 16384*1024
  const size_t NW = 1048576ull;       // 1024*1024
  const size_t total = NX + 4*NW;
  size_t stride = (size_t)gridDim.x * blockDim.x;
  for (size_t i = (size_t)blockIdx.x*blockDim.x + threadIdx.x; i < total; i += stride){
    if (i < NX) {
      xb[i] = f2b(x[i]);
    } else if (i < NX + NW) {
      size_t j = i - NX;
      wqkvb[(j>>10)*3072 + (j&1023)] = f2b(wq[j]);
    } else if (i < NX + 2*NW) {
      size_t j = i - NX - NW;
      wqkvb[(j>>10)*3072 + 1024 + (j&1023)] = f2b(wk[j]);
    } else if (i < NX + 3*NW) {
      size_t j = i - NX - 2*NW;
      wqkvb[(j>>10)*3072 + 2048 + (j&1023)] = f2b(wv[j]);
    } else {
      size_t j = i - NX - 3*NW;
      wob[j] = f2b(wo[j]);
    }
  }
}

// ---------------- bf16 MFMA GEMM: C[M][N] = A[M][K] * Bm[K][N] ----------------
// 128x128 tile, BK=32, 4 waves each owning 64x64 (4x4 frags of 16x16x32).
// MODE 0: fp32 C.  MODE 1: qkv split (N=3072), q scaled by 0.125, bf16 out.
template<int MODE>
__global__ __launch_bounds__(256) void gemm_kernel(
    const u16* __restrict__ A, const u16* __restrict__ Bm,
    float* __restrict__ C,
    u16* __restrict__ Qp, u16* __restrict__ Kp, u16* __restrict__ Vp,
    int M, int N, int K)
{
  __shared__ __align__(16) u16 As[128][40];   // padded 32->40 (bank spread)
  __shared__ __align__(16) u16 Bs[128][40];   // B transposed: Bs[n][k]
  const int bx = blockIdx.x, by = blockIdx.y;
  const int m0 = by*128, n0 = bx*128;
  const int tid = threadIdx.x;
  const int lane = tid & 63, w = tid >> 6;
  const int wr = w >> 1, wc = w & 1;

  f32x4 acc[4][4];
  #pragma unroll
  for (int i=0;i<4;i++)
    #pragma unroll
    for (int j=0;j<4;j++) acc[i][j] = (f32x4)0.f;

  for (int k0 = 0; k0 < K; k0 += 32) {
    // stage A: thread -> row tid>>1, 16 bf16 at col (tid&1)*16
    {
      int r = tid >> 1, cs = (tid & 1) * 16;
      const u16* src = A + (size_t)(m0 + r)*K + k0 + cs;
      uint4 v0 = *(const uint4*)(src);
      uint4 v1 = *(const uint4*)(src + 8);
      *(uint4*)&As[r][cs]     = v0;
      *(uint4*)&As[r][cs + 8] = v1;
    }
    // stage B transposed: 2 loads of 8 bf16 along n, scatter to Bs[n][k]
    #pragma unroll
    for (int i=0;i<2;i++){
      int L = tid + 256*i;
      int kr = L >> 4;          // 0..31
      int g  = L & 15;          // n-octet
      const u16* src = Bm + (size_t)(k0+kr)*N + n0 + g*8;
      uint4 vv = *(const uint4*)src;
      const u16* pv = (const u16*)&vv;
      #pragma unroll
      for (int j=0;j<8;j++) Bs[g*8+j][kr] = pv[j];
    }
    __syncthreads();
    bf16x8 af[4], bfr[4];
    const int kk = (lane >> 4) * 8;
    #pragma unroll
    for (int mi=0; mi<4; mi++)
      af[mi] = *(const bf16x8*)&As[wr*64 + mi*16 + (lane&15)][kk];
    #pragma unroll
    for (int nj=0; nj<4; nj++)
      bfr[nj] = *(const bf16x8*)&Bs[wc*64 + nj*16 + (lane&15)][kk];
    #pragma unroll
    for (int mi=0; mi<4; mi++)
      #pragma unroll
      for (int nj=0; nj<4; nj++)
        acc[mi][nj] = __builtin_amdgcn_mfma_f32_16x16x32_bf16(af[mi], bfr[nj], acc[mi][nj], 0, 0, 0);
    __syncthreads();
  }

  // epilogue: C/D layout col=lane&15, row=(lane>>4)*4+reg  [m89-verified]
  if (MODE == 0) {
    #pragma unroll
    for (int mi=0; mi<4; mi++)
      #pragma unroll
      for (int nj=0; nj<4; nj++){
        int row = m0 + wr*64 + mi*16 + ((lane>>4)<<2);
        int col = n0 + wc*64 + nj*16 + (lane&15);
        #pragma unroll
        for (int r=0;r<4;r++)
          C[(size_t)(row+r)*N + col] = acc[mi][nj][r];
      }
  } else {
    int mat = n0 >> 10;                       // 128-wide tile never straddles matrices
    u16* dst = (mat==0) ? Qp : (mat==1 ? Kp : Vp);
    float sc = (mat==0) ? 0.125f : 1.0f;      // q pre-scaled by 1/sqrt(DH)
    int cc0 = n0 & 1023;
    #pragma unroll
    for (int mi=0; mi<4; mi++)
      #pragma unroll
      for (int nj=0; nj<4; nj++){
        int row = m0 + wr*64 + mi*16 + ((lane>>4)<<2);
        int col = cc0 + wc*64 + nj*16 + (lane&15);
        #pragma unroll
        for (int r=0;r<4;r++)
          dst[(size_t)(row+r)*1024 + col] = f2b(acc[mi][nj][r]*sc);
      }
  }
}

// ---------------- per-level spans ----------------
// One wave per (b, chunk, h). lane = d. Two passes: maxpool(q,k), then online
// softmax of (sq . k_j) accumulating v_j.
template<int LVL>
__global__ __launch_bounds__(256) void span_kernel(
    const u16* __restrict__ q, const u16* __restrict__ k, const u16* __restrict__ v,
    u16* __restrict__ spank, u16* __restrict__ spanv)  // pre-offset for level
{
  const int c = 1 << LVL;
  const int n = T_ >> LVL;
  int wid  = blockIdx.x * 4 + (threadIdx.x >> 6);
  int lane = threadIdx.x & 63;
  int h = wid % H_;
  int rest = wid / H_;
  int m = rest % n;
  int b = rest / n;
  size_t base = ((size_t)(b*T_ + m*c)*H_ + h)*DHD + lane;
  const size_t stride = H_*DHD;

  float maxk = -1e30f, maxq = -1e30f;
  for (int j=0;j<c;j++){
    maxk = fmaxf(maxk, b2f(k[base + (size_t)j*stride]));
    maxq = fmaxf(maxq, b2f(q[base + (size_t)j*stride]));
  }
  float mrun = -1e30f, srun = 0.f, accd = 0.f;
  for (int j=0;j<c;j++){
    float kd = b2f(k[base + (size_t)j*stride]);
    float lg = wave_sum(maxq * kd);
    float vd = b2f(v[base + (size_t)j*stride]);
    float nm = fmaxf(mrun, lg);
    float f  = expf(mrun - nm);
    float p  = expf(lg - nm);
    srun = srun*f + p;
    accd = accd*f + p*vd;
    mrun = nm;
  }
  size_t so = ((size_t)(b*n + m)*H_ + h)*DHD + lane;
  spank[so] = f2b(maxk);
  spanv[so] = f2b(accd / srun);
}

// ---------------- merge: 12-way softmax over {self, levels 0..10} ----------------
__global__ __launch_bounds__(256) void merge_kernel(
    const u16* __restrict__ q, const u16* __restrict__ k, const u16* __restrict__ v,
    const u16* __restrict__ spank, const u16* __restrict__ spanv,
    u16* __restrict__ merged)
{
  int wid  = blockIdx.x*4 + (threadIdx.x>>6);
  int lane = threadIdx.x & 63;
  int h = wid & 15;
  int t = (wid >> 4) & (T_-1);
  int b = wid >> 15;
  size_t qi = ((size_t)(b*T_ + t)*H_ + h)*DHD + lane;
  float qd = b2f(q[qi]);
  float kd = b2f(k[qi]);
  float vd = b2f(v[qi]);
  float lg[12], val[12];
  lg[0]  = wave_sum(qd*kd);   // self logit (q already scaled)
  val[0] = vd;
  #pragma unroll
  for (int l=0; l<LOGL; l++){
    const int c = 1<<l;
    float L = -1e30f, V = 0.f;
    if (t >= c) {
      int m = (t - c) >> l;
      if ((m & 1) == 0) {           // preceding chunk must have even index
        float skd, svd;
        if (l == 0) {
          size_t ii = ((size_t)(b*T_ + (t-1))*H_ + h)*DHD + lane;
          skd = b2f(k[ii]); svd = b2f(v[ii]);
        } else {
          const int n = T_>>l;
          size_t choff = (size_t)(B_*(2048 - (4096>>l)));   // chunks before level l
          size_t si = ((choff + (size_t)b*n + m)*H_ + h)*DHD + lane;
          skd = b2f(spank[si]); svd = b2f(spanv[si]);
        }
        L = wave_sum(qd*skd);
        V = svd;
      }
    }
    lg[l+1] = L; val[l+1] = V;
  }
  float M = lg[0];
  #pragma unroll
  for (int i=1;i<12;i++) M = fmaxf(M, lg[i]);
  float s = 0.f, acc = 0.f;
  #pragma unroll
  for (int i=0;i<12;i++){ float p = expf(lg[i]-M); s += p; acc += p*val[i]; }
  merged[(size_t)(b*T_+t)*1024 + h*64 + lane] = f2b(acc/s);
}

// ---------------- launch ----------------
extern "C" void kernel_launch(void* const* d_in, const int* in_sizes, int n_in,
                              void* d_out, int out_size, void* d_ws, size_t ws_size,
                              hipStream_t stream) {
  (void)in_sizes; (void)n_in; (void)out_size; (void)ws_size;
  const float* x  = (const float*)d_in[0];
  const float* Wq = (const float*)d_in[1];
  const float* Wk = (const float*)d_in[2];
  const float* Wv = (const float*)d_in[3];
  const float* Wo = (const float*)d_in[4];
  float* out = (float*)d_out;

  uint8_t* w = (uint8_t*)d_ws;
  u16* xb    = (u16*)(w);                   // 32 MB  (reused as `merged` later)
  u16* qb    = (u16*)(w + 33554432ull);     // 32 MB
  u16* kb    = (u16*)(w + 67108864ull);     // 32 MB
  u16* vb    = (u16*)(w + 100663296ull);    // 32 MB
  u16* spank = (u16*)(w + 134217728ull);    // 32 MB
  u16* spanv = (u16*)(w + 167772160ull);    // 32 MB
  u16* wqkvb = (u16*)(w + 201326592ull);    // 6 MB
  u16* wob   = (u16*)(w + 207618048ull);    // 2 MB
  // total ws use: ~200 MB

  convert_kernel<<<2048, 256, 0, stream>>>(x, Wq, Wk, Wv, Wo, xb, wqkvb, wob);

  gemm_kernel<1><<<dim3(24,128), 256, 0, stream>>>(xb, wqkvb, nullptr, qb, kb, vb,
                                                   16384, 3072, 1024);

  #define SPAN(L) do { \
    size_t choff = (size_t)(B_*(2048 - (4096>>(L)))); \
    span_kernel<L><<<(65536>>(L)), 256, 0, stream>>>(qb, kb, vb, \
        spank + choff*1024, spanv + choff*1024); \
  } while(0)
  SPAN(1); SPAN(2); SPAN(3); SPAN(4); SPAN(5);
  SPAN(6); SPAN(7); SPAN(8); SPAN(9); SPAN(10);
  #undef SPAN

  merge_kernel<<<65536, 256, 0, stream>>>(qb, kb, vb, spank, spanv, xb /*merged*/);

  gemm_kernel<0><<<dim3(8,128), 256, 0, stream>>>(xb, wob, out, nullptr, nullptr, nullptr,
                                                  16384, 1024, 1024);
}

// Round 2
// 732.130 us; speedup vs baseline: 2.2775x; 2.2775x over previous
//
#include <hip/hip_runtime.h>
#include <hip/hip_bf16.h>
#include <stdint.h>

// SelfAttLogn: B=8 T=2048 DM=1024 H=16 DH=64, LOG_LEN=11
// convert x -> bf16 | transpose-convert W -> bf16 B^T | QKV gemm (m97 structure)
// | spans (small: wave-serial; large: block 3-phase) | merge | out gemm

typedef unsigned short u16;
typedef __attribute__((ext_vector_type(8))) short bf16x8;
typedef __attribute__((ext_vector_type(4))) float f32x4;

#define B_ 8
#define T_ 2048
#define H_ 16
#define DHD 64
#define LOGL 11

__device__ __forceinline__ float b2f(u16 u){
  union { float f; unsigned int i; } x; x.i = ((unsigned int)u) << 16; return x.f;
}
__device__ __forceinline__ u16 f2b(float f){
  union { float f; unsigned int i; } x; x.f = f;
  unsigned int r = x.i + 0x7fffu + ((x.i >> 16) & 1u);
  return (u16)(r >> 16);
}
__device__ __forceinline__ float wave_sum(float v){
  #pragma unroll
  for (int o = 32; o > 0; o >>= 1) v += __shfl_xor(v, o);
  return v;
}
__device__ __forceinline__ void gload_lds16(const void* g, void* l) {
  __builtin_amdgcn_global_load_lds((const __attribute__((address_space(1))) void*)g,
                                   (__attribute__((address_space(3))) void*)l, 16, 0, 0);
}

// ---------------- convert x to bf16 (vectorized) ----------------
__global__ __launch_bounds__(256) void convert_x_kernel(
    const float* __restrict__ x, u16* __restrict__ xb)
{
  size_t i = ((size_t)blockIdx.x*256 + threadIdx.x)*8;
  float4 a = *(const float4*)(x+i);
  float4 b = *(const float4*)(x+i+4);
  u16 o[8] = {f2b(a.x),f2b(a.y),f2b(a.z),f2b(a.w),f2b(b.x),f2b(b.y),f2b(b.z),f2b(b.w)};
  *(uint4*)(xb+i) = *(uint4*)o;
}

// ---------------- transpose-convert weights: out[n][k] = in[k][n] as bf16 ----------
__global__ __launch_bounds__(256) void wtrans_kernel(
    const float* __restrict__ w0, const float* __restrict__ w1,
    const float* __restrict__ w2, const float* __restrict__ w3,
    u16* __restrict__ wqkvT, u16* __restrict__ woT)
{
  __shared__ u16 tile[64][65];
  int mat = blockIdx.z;
  const float* src = (mat==0)?w0:(mat==1)?w1:(mat==2)?w2:w3;
  u16* dst = (mat<3) ? (wqkvT + (size_t)mat*1048576ull) : woT;
  int r0 = blockIdx.y*64, c0 = blockIdx.x*64;
  int t = threadIdx.x;
  int tr = t>>4, tc = (t&15)*4;
  #pragma unroll
  for (int i=0;i<4;i++){
    int r = tr + i*16;
    float4 a = *(const float4*)(src + (size_t)(r0+r)*1024 + c0 + tc);
    tile[tc+0][r] = f2b(a.x);
    tile[tc+1][r] = f2b(a.y);
    tile[tc+2][r] = f2b(a.z);
    tile[tc+3][r] = f2b(a.w);
  }
  __syncthreads();
  #pragma unroll
  for (int i=0;i<4;i++){
    int rr = tr + i*16;                 // output row-in-tile = source col
    uint2 o; u16* p = (u16*)&o;
    p[0]=tile[rr][tc+0]; p[1]=tile[rr][tc+1]; p[2]=tile[rr][tc+2]; p[3]=tile[rr][tc+3];
    *(uint2*)(dst + (size_t)(c0+rr)*1024 + r0 + tc) = o;
  }
}

// ---------------- bf16 MFMA GEMM (m97 structure): C = A[M][K] * BT[N][K]^T ----------
// 128x128 tile, BK=32, global_load_lds width=16, linear LDS, 4 waves x (64x64).
// MODE 0: fp32 C.  MODE 1: qkv split (N=3072), q scaled 0.125, bf16 out.
template<int MODE>
__global__ __launch_bounds__(256) void gemm_kernel(
    const u16* __restrict__ A, const u16* __restrict__ BT,
    float* __restrict__ C,
    u16* __restrict__ Qp, u16* __restrict__ Kp, u16* __restrict__ Vp,
    int M, int N, int K)
{
  __shared__ __align__(16) u16 As[128*32];
  __shared__ __align__(16) u16 Bs[128*32];
  const int bx = blockIdx.x, by = blockIdx.y;
  const int m0 = by*128, n0 = bx*128;
  const int tid = threadIdx.x;
  const int lane = tid & 63, w = tid >> 6;
  const int wr = w >> 1, wc = w & 1;

  f32x4 acc[4][4];
  #pragma unroll
  for (int i=0;i<4;i++)
    #pragma unroll
    for (int j=0;j<4;j++) acc[i][j] = (f32x4)0.f;

  const int srow = tid >> 2;            // 0..63
  const int scol = (tid & 3) * 8;       // 0,8,16,24
  const u16* ga0 = A  + (size_t)(m0 + srow)*K + scol;
  const u16* gb0 = BT + (size_t)(n0 + srow)*K + scol;
  u16* la = &As[tid*8];                 // = srow*32 + scol
  u16* lb = &Bs[tid*8];

  for (int k0 = 0; k0 < K; k0 += 32) {
    gload_lds16(ga0 + k0,                 la);
    gload_lds16(ga0 + k0 + (size_t)64*K,  la + 64*32);
    gload_lds16(gb0 + k0,                 lb);
    gload_lds16(gb0 + k0 + (size_t)64*K,  lb + 64*32);
    __syncthreads();

    bf16x8 af[4], bfr[4];
    const int kk = (lane >> 4) * 8;
    #pragma unroll
    for (int mi=0; mi<4; mi++)
      af[mi] = *(const bf16x8*)&As[(wr*64 + mi*16 + (lane&15))*32 + kk];
    #pragma unroll
    for (int nj=0; nj<4; nj++)
      bfr[nj] = *(const bf16x8*)&Bs[(wc*64 + nj*16 + (lane&15))*32 + kk];
    #pragma unroll
    for (int mi=0; mi<4; mi++)
      #pragma unroll
      for (int nj=0; nj<4; nj++)
        acc[mi][nj] = __builtin_amdgcn_mfma_f32_16x16x32_bf16(af[mi], bfr[nj], acc[mi][nj], 0, 0, 0);
    __syncthreads();
  }

  // epilogue: C/D layout col=lane&15, row=(lane>>4)*4+reg  [m89-verified]
  if (MODE == 0) {
    #pragma unroll
    for (int mi=0; mi<4; mi++)
      #pragma unroll
      for (int nj=0; nj<4; nj++){
        int row = m0 + wr*64 + mi*16 + ((lane>>4)<<2);
        int col = n0 + wc*64 + nj*16 + (lane&15);
        #pragma unroll
        for (int r=0;r<4;r++)
          C[(size_t)(row+r)*N + col] = acc[mi][nj][r];
      }
  } else {
    int mat = n0 >> 10;
    u16* dst = (mat==0) ? Qp : (mat==1 ? Kp : Vp);
    float sc = (mat==0) ? 0.125f : 1.0f;
    int cc0 = n0 & 1023;
    #pragma unroll
    for (int mi=0; mi<4; mi++)
      #pragma unroll
      for (int nj=0; nj<4; nj++){
        int row = m0 + wr*64 + mi*16 + ((lane>>4)<<2);
        int col = cc0 + wc*64 + nj*16 + (lane&15);
        #pragma unroll
        for (int r=0;r<4;r++)
          dst[(size_t)(row+r)*1024 + col] = f2b(acc[mi][nj][r]*sc);
      }
  }
}

// ---------------- spans, small levels (c<=32): one wave per chunk ----------------
template<int LVL>
__global__ __launch_bounds__(256) void span_kernel(
    const u16* __restrict__ q, const u16* __restrict__ k, const u16* __restrict__ v,
    u16* __restrict__ spank, u16* __restrict__ spanv)
{
  const int c = 1 << LVL;
  const int n = T_ >> LVL;
  int wid  = blockIdx.x * 4 + (threadIdx.x >> 6);
  int lane = threadIdx.x & 63;
  int h = wid % H_;
  int rest = wid / H_;
  int m = rest % n;
  int b = rest / n;
  size_t base = ((size_t)(b*T_ + m*c)*H_ + h)*DHD + lane;
  const size_t stride = H_*DHD;

  float maxk = -1e30f, maxq = -1e30f;
  for (int j=0;j<c;j++){
    maxk = fmaxf(maxk, b2f(k[base + (size_t)j*stride]));
    maxq = fmaxf(maxq, b2f(q[base + (size_t)j*stride]));
  }
  float mrun = -1e30f, srun = 0.f, accd = 0.f;
  for (int j=0;j<c;j++){
    float kd = b2f(k[base + (size_t)j*stride]);
    float lg = wave_sum(maxq * kd);
    float vd = b2f(v[base + (size_t)j*stride]);
    float nm = fmaxf(mrun, lg);
    float f  = expf(mrun - nm);
    float p  = expf(lg - nm);
    srun = srun*f + p;
    accd = accd*f + p*vd;
    mrun = nm;
  }
  size_t so = ((size_t)(b*n + m)*H_ + h)*DHD + lane;
  spank[so] = f2b(maxk);
  spanv[so] = f2b(accd / srun);
}

// ---------------- spans, large levels (c>=64): one block per chunk, 3 phases ------
template<int LVL>
__global__ __launch_bounds__(256) void span_large_kernel(
    const u16* __restrict__ q, const u16* __restrict__ k, const u16* __restrict__ v,
    u16* __restrict__ spank, u16* __restrict__ spanv)
{
  const int c = 1 << LVL;
  const int n = T_ >> LVL;
  const int JW = c >> 2;                 // per-wave j span (>=16)
  int bid = blockIdx.x;
  int h = bid & (H_-1);
  int rest = bid >> 4;
  int m = rest % n;
  int b = rest / n;
  int tid = threadIdx.x, lane = tid & 63, w = tid >> 6;
  size_t base = ((size_t)(b*T_ + m*c)*H_ + h)*DHD;
  const int str = H_*DHD;

  __shared__ float sq_sh[DHD];
  __shared__ float red[4][DHD];
  __shared__ float e_sh[1024];
  __shared__ float mred[4], sred[4];

  // phase 1: lane=d coalesced max over q and k (wave-partitioned j)
  float mq = -1e30f, mk = -1e30f;
  int j0 = w*JW, j1 = j0 + JW;
  for (int j = j0; j < j1; ++j) {
    mq = fmaxf(mq, b2f(q[base + (size_t)j*str + lane]));
    mk = fmaxf(mk, b2f(k[base + (size_t)j*str + lane]));
  }
  red[w][lane] = mq;
  __syncthreads();
  if (w == 0)
    sq_sh[lane] = fmaxf(fmaxf(red[0][lane], red[1][lane]),
                        fmaxf(red[2][lane], red[3][lane]));
  __syncthreads();
  red[w][lane] = mk;
  __syncthreads();
  mk = fmaxf(fmaxf(red[0][lane], red[1][lane]), fmaxf(red[2][lane], red[3][lane]));

  // phase 2: thread=j logits via LDS-broadcast sq (k rows L1-hot from phase 1)
  float lmax = -1e30f;
  for (int j = tid; j < c; j += 256) {
    const u16* kr = k + base + (size_t)j*str;
    float dot = 0.f;
    #pragma unroll
    for (int d0 = 0; d0 < 64; d0 += 8) {
      bf16x8 kv = *(const bf16x8*)(kr + d0);
      #pragma unroll
      for (int e = 0; e < 8; ++e)
        dot += sq_sh[d0+e] * b2f(((const u16*)&kv)[e]);
    }
    e_sh[j] = dot;
    lmax = fmaxf(lmax, dot);
  }
  #pragma unroll
  for (int o=32;o>0;o>>=1) lmax = fmaxf(lmax, __shfl_xor(lmax,o));
  if (lane==0) mred[w] = lmax;
  __syncthreads();
  float M = fmaxf(fmaxf(mred[0],mred[1]),fmaxf(mred[2],mred[3]));
  float spart = 0.f;
  for (int j = tid; j < c; j += 256) {
    float e = expf(e_sh[j] - M);
    e_sh[j] = e;
    spart += e;
  }
  #pragma unroll
  for (int o=32;o>0;o>>=1) spart += __shfl_xor(spart,o);
  if (lane==0) sred[w] = spart;
  __syncthreads();
  float S = sred[0]+sred[1]+sred[2]+sred[3];

  // phase 3: lane=d weighted V accumulation over wave's j span
  float acc = 0.f;
  for (int j = j0; j < j1; ++j)
    acc += e_sh[j] * b2f(v[base + (size_t)j*str + lane]);
  red[w][lane] = acc;
  __syncthreads();
  if (w == 0) {
    float a = red[0][lane]+red[1][lane]+red[2][lane]+red[3][lane];
    size_t so = ((size_t)(b*n + m)*H_ + h)*DHD + lane;
    spanv[so] = f2b(a / S);
    spank[so] = f2b(mk);
  }
}

// ---------------- merge: 12-way softmax over {self, levels 0..10} ----------------
__global__ __launch_bounds__(256) void merge_kernel(
    const u16* __restrict__ q, const u16* __restrict__ k, const u16* __restrict__ v,
    const u16* __restrict__ spank, const u16* __restrict__ spanv,
    u16* __restrict__ merged)
{
  int wid  = blockIdx.x*4 + (threadIdx.x>>6);
  int lane = threadIdx.x & 63;
  int h = wid & 15;
  int t = (wid >> 4) & (T_-1);
  int b = wid >> 15;
  size_t qi = ((size_t)(b*T_ + t)*H_ + h)*DHD + lane;
  float qd = b2f(q[qi]);
  float kd = b2f(k[qi]);
  float vd = b2f(v[qi]);
  float lg[12], val[12];
  lg[0]  = wave_sum(qd*kd);
  val[0] = vd;
  #pragma unroll
  for (int l=0; l<LOGL; l++){
    const int c = 1<<l;
    float L = -1e30f, V = 0.f;
    if (t >= c) {
      int m = (t - c) >> l;
      if ((m & 1) == 0) {
        float skd, svd;
        if (l == 0) {
          size_t ii = ((size_t)(b*T_ + (t-1))*H_ + h)*DHD + lane;
          skd = b2f(k[ii]); svd = b2f(v[ii]);
        } else {
          const int n = T_>>l;
          size_t choff = (size_t)(B_*(2048 - (4096>>l)));
          size_t si = ((choff + (size_t)b*n + m)*H_ + h)*DHD + lane;
          skd = b2f(spank[si]); svd = b2f(spanv[si]);
        }
        L = wave_sum(qd*skd);
        V = svd;
      }
    }
    lg[l+1] = L; val[l+1] = V;
  }
  float M = lg[0];
  #pragma unroll
  for (int i=1;i<12;i++) M = fmaxf(M, lg[i]);
  float s = 0.f, acc = 0.f;
  #pragma unroll
  for (int i=0;i<12;i++){ float p = expf(lg[i]-M); s += p; acc += p*val[i]; }
  merged[(size_t)(b*T_+t)*1024 + h*64 + lane] = f2b(acc/s);
}

// ---------------- launch ----------------
extern "C" void kernel_launch(void* const* d_in, const int* in_sizes, int n_in,
                              void* d_out, int out_size, void* d_ws, size_t ws_size,
                              hipStream_t stream) {
  (void)in_sizes; (void)n_in; (void)out_size; (void)ws_size;
  const float* x  = (const float*)d_in[0];
  const float* Wq = (const float*)d_in[1];
  const float* Wk = (const float*)d_in[2];
  const float* Wv = (const float*)d_in[3];
  const float* Wo = (const float*)d_in[4];
  float* out = (float*)d_out;

  uint8_t* w = (uint8_t*)d_ws;
  u16* xb     = (u16*)(w);                   // 32 MB (reused as merged)
  u16* qb     = (u16*)(w + 33554432ull);     // 32 MB
  u16* kb     = (u16*)(w + 67108864ull);     // 32 MB
  u16* vb     = (u16*)(w + 100663296ull);    // 32 MB
  u16* spank  = (u16*)(w + 134217728ull);    // 32 MB
  u16* spanv  = (u16*)(w + 167772160ull);    // 32 MB
  u16* wqkvT  = (u16*)(w + 201326592ull);    // 6 MB  [3072][1024] B^T
  u16* woT    = (u16*)(w + 207618048ull);    // 2 MB  [1024][1024] B^T

  convert_x_kernel<<<8192, 256, 0, stream>>>(x, xb);
  wtrans_kernel<<<dim3(16,16,4), 256, 0, stream>>>(Wq, Wk, Wv, Wo, wqkvT, woT);

  gemm_kernel<1><<<dim3(24,128), 256, 0, stream>>>(xb, wqkvT, nullptr, qb, kb, vb,
                                                   16384, 3072, 1024);

  #define SPAN(L) do { \
    size_t choff = (size_t)(B_*(2048 - (4096>>(L)))); \
    span_kernel<L><<<(65536>>(L)), 256, 0, stream>>>(qb, kb, vb, \
        spank + choff*1024, spanv + choff*1024); \
  } while(0)
  #define SPANL(L) do { \
    size_t choff = (size_t)(B_*(2048 - (4096>>(L)))); \
    span_large_kernel<L><<<(262144>>(L)), 256, 0, stream>>>(qb, kb, vb, \
        spank + choff*1024, spanv + choff*1024); \
  } while(0)
  SPAN(1); SPAN(2); SPAN(3); SPAN(4); SPAN(5);
  SPANL(6); SPANL(7); SPANL(8); SPANL(9); SPANL(10);
  #undef SPAN
  #undef SPANL

  merge_kernel<<<65536, 256, 0, stream>>>(qb, kb, vb, spank, spanv, xb /*merged*/);

  gemm_kernel<0><<<dim3(8,128), 256, 0, stream>>>(xb, woT, out, nullptr, nullptr, nullptr,
                                                  16384, 1024, 1024);
}

// Round 3
// 548.353 us; speedup vs baseline: 3.0408x; 1.3351x over previous
//
#include <hip/hip_runtime.h>
#include <hip/hip_bf16.h>
#include <stdint.h>

// SelfAttLogn: B=8 T=2048 DM=1024 H=16 DH=64, LOG_LEN=11
// convert x -> bf16 | transpose-convert W | QKV gemm (m97) | spans | merge (thread-per-elem) | out gemm

typedef unsigned short u16;
typedef __attribute__((ext_vector_type(8))) short bf16x8;
typedef __attribute__((ext_vector_type(4))) float f32x4;

#define B_ 8
#define T_ 2048
#define H_ 16
#define DHD 64
#define LOGL 11

__device__ __forceinline__ float b2f(u16 u){
  union { float f; unsigned int i; } x; x.i = ((unsigned int)u) << 16; return x.f;
}
__device__ __forceinline__ float bl(unsigned u){
  union { float f; unsigned int i; } x; x.i = u << 16; return x.f;
}
__device__ __forceinline__ float bh(unsigned u){
  union { float f; unsigned int i; } x; x.i = u & 0xffff0000u; return x.f;
}
__device__ __forceinline__ u16 f2b(float f){
  union { float f; unsigned int i; } x; x.f = f;
  unsigned int r = x.i + 0x7fffu + ((x.i >> 16) & 1u);
  return (u16)(r >> 16);
}
__device__ __forceinline__ float wave_sum(float v){
  #pragma unroll
  for (int o = 32; o > 0; o >>= 1) v += __shfl_xor(v, o);
  return v;
}
__device__ __forceinline__ void gload_lds16(const void* g, void* l) {
  __builtin_amdgcn_global_load_lds((const __attribute__((address_space(1))) void*)g,
                                   (__attribute__((address_space(3))) void*)l, 16, 0, 0);
}

// ---------------- convert x to bf16 (vectorized) ----------------
__global__ __launch_bounds__(256) void convert_x_kernel(
    const float* __restrict__ x, u16* __restrict__ xb)
{
  size_t i = ((size_t)blockIdx.x*256 + threadIdx.x)*8;
  float4 a = *(const float4*)(x+i);
  float4 b = *(const float4*)(x+i+4);
  u16 o[8] = {f2b(a.x),f2b(a.y),f2b(a.z),f2b(a.w),f2b(b.x),f2b(b.y),f2b(b.z),f2b(b.w)};
  *(uint4*)(xb+i) = *(uint4*)o;
}

// ---------------- transpose-convert weights: out[n][k] = in[k][n] as bf16 ----------
__global__ __launch_bounds__(256) void wtrans_kernel(
    const float* __restrict__ w0, const float* __restrict__ w1,
    const float* __restrict__ w2, const float* __restrict__ w3,
    u16* __restrict__ wqkvT, u16* __restrict__ woT)
{
  __shared__ u16 tile[64][65];
  int mat = blockIdx.z;
  const float* src = (mat==0)?w0:(mat==1)?w1:(mat==2)?w2:w3;
  u16* dst = (mat<3) ? (wqkvT + (size_t)mat*1048576ull) : woT;
  int r0 = blockIdx.y*64, c0 = blockIdx.x*64;
  int t = threadIdx.x;
  int tr = t>>4, tc = (t&15)*4;
  #pragma unroll
  for (int i=0;i<4;i++){
    int r = tr + i*16;
    float4 a = *(const float4*)(src + (size_t)(r0+r)*1024 + c0 + tc);
    tile[tc+0][r] = f2b(a.x);
    tile[tc+1][r] = f2b(a.y);
    tile[tc+2][r] = f2b(a.z);
    tile[tc+3][r] = f2b(a.w);
  }
  __syncthreads();
  #pragma unroll
  for (int i=0;i<4;i++){
    int rr = tr + i*16;
    uint2 o; u16* p = (u16*)&o;
    p[0]=tile[rr][tc+0]; p[1]=tile[rr][tc+1]; p[2]=tile[rr][tc+2]; p[3]=tile[rr][tc+3];
    *(uint2*)(dst + (size_t)(c0+rr)*1024 + r0 + tc) = o;
  }
}

// ---------------- bf16 MFMA GEMM (m97 structure): C = A[M][K] * BT[N][K]^T ----------
template<int MODE>
__global__ __launch_bounds__(256) void gemm_kernel(
    const u16* __restrict__ A, const u16* __restrict__ BT,
    float* __restrict__ C,
    u16* __restrict__ Qp, u16* __restrict__ Kp, u16* __restrict__ Vp,
    int M, int N, int K)
{
  __shared__ __align__(16) u16 As[128*32];
  __shared__ __align__(16) u16 Bs[128*32];
  const int bx = blockIdx.x, by = blockIdx.y;
  const int m0 = by*128, n0 = bx*128;
  const int tid = threadIdx.x;
  const int lane = tid & 63, w = tid >> 6;
  const int wr = w >> 1, wc = w & 1;

  f32x4 acc[4][4];
  #pragma unroll
  for (int i=0;i<4;i++)
    #pragma unroll
    for (int j=0;j<4;j++) acc[i][j] = (f32x4)0.f;

  const int srow = tid >> 2;
  const int scol = (tid & 3) * 8;
  const u16* ga0 = A  + (size_t)(m0 + srow)*K + scol;
  const u16* gb0 = BT + (size_t)(n0 + srow)*K + scol;
  u16* la = &As[tid*8];
  u16* lb = &Bs[tid*8];

  for (int k0 = 0; k0 < K; k0 += 32) {
    gload_lds16(ga0 + k0,                 la);
    gload_lds16(ga0 + k0 + (size_t)64*K,  la + 64*32);
    gload_lds16(gb0 + k0,                 lb);
    gload_lds16(gb0 + k0 + (size_t)64*K,  lb + 64*32);
    __syncthreads();

    bf16x8 af[4], bfr[4];
    const int kk = (lane >> 4) * 8;
    #pragma unroll
    for (int mi=0; mi<4; mi++)
      af[mi] = *(const bf16x8*)&As[(wr*64 + mi*16 + (lane&15))*32 + kk];
    #pragma unroll
    for (int nj=0; nj<4; nj++)
      bfr[nj] = *(const bf16x8*)&Bs[(wc*64 + nj*16 + (lane&15))*32 + kk];
    #pragma unroll
    for (int mi=0; mi<4; mi++)
      #pragma unroll
      for (int nj=0; nj<4; nj++)
        acc[mi][nj] = __builtin_amdgcn_mfma_f32_16x16x32_bf16(af[mi], bfr[nj], acc[mi][nj], 0, 0, 0);
    __syncthreads();
  }

  if (MODE == 0) {
    #pragma unroll
    for (int mi=0; mi<4; mi++)
      #pragma unroll
      for (int nj=0; nj<4; nj++){
        int row = m0 + wr*64 + mi*16 + ((lane>>4)<<2);
        int col = n0 + wc*64 + nj*16 + (lane&15);
        #pragma unroll
        for (int r=0;r<4;r++)
          C[(size_t)(row+r)*N + col] = acc[mi][nj][r];
      }
  } else {
    int mat = n0 >> 10;
    u16* dst = (mat==0) ? Qp : (mat==1 ? Kp : Vp);
    float sc = (mat==0) ? 0.125f : 1.0f;
    int cc0 = n0 & 1023;
    #pragma unroll
    for (int mi=0; mi<4; mi++)
      #pragma unroll
      for (int nj=0; nj<4; nj++){
        int row = m0 + wr*64 + mi*16 + ((lane>>4)<<2);
        int col = cc0 + wc*64 + nj*16 + (lane&15);
        #pragma unroll
        for (int r=0;r<4;r++)
          dst[(size_t)(row+r)*1024 + col] = f2b(acc[mi][nj][r]*sc);
      }
  }
}

// ---------------- spans, small levels (c<=32): one wave per chunk ----------------
template<int LVL>
__global__ __launch_bounds__(256) void span_kernel(
    const u16* __restrict__ q, const u16* __restrict__ k, const u16* __restrict__ v,
    u16* __restrict__ spank, u16* __restrict__ spanv)
{
  const int c = 1 << LVL;
  const int n = T_ >> LVL;
  int wid  = blockIdx.x * 4 + (threadIdx.x >> 6);
  int lane = threadIdx.x & 63;
  int h = wid % H_;
  int rest = wid / H_;
  int m = rest % n;
  int b = rest / n;
  size_t base = ((size_t)(b*T_ + m*c)*H_ + h)*DHD + lane;
  const size_t stride = H_*DHD;

  float maxk = -1e30f, maxq = -1e30f;
  for (int j=0;j<c;j++){
    maxk = fmaxf(maxk, b2f(k[base + (size_t)j*stride]));
    maxq = fmaxf(maxq, b2f(q[base + (size_t)j*stride]));
  }
  float mrun = -1e30f, srun = 0.f, accd = 0.f;
  for (int j=0;j<c;j++){
    float kd = b2f(k[base + (size_t)j*stride]);
    float lg = wave_sum(maxq * kd);
    float vd = b2f(v[base + (size_t)j*stride]);
    float nm = fmaxf(mrun, lg);
    float f  = __expf(mrun - nm);
    float p  = __expf(lg - nm);
    srun = srun*f + p;
    accd = accd*f + p*vd;
    mrun = nm;
  }
  size_t so = ((size_t)(b*n + m)*H_ + h)*DHD + lane;
  spank[so] = f2b(maxk);
  spanv[so] = f2b(accd / srun);
}

// ---------------- spans, large levels (c>=64): one block per chunk, 3 phases ------
template<int LVL>
__global__ __launch_bounds__(256) void span_large_kernel(
    const u16* __restrict__ q, const u16* __restrict__ k, const u16* __restrict__ v,
    u16* __restrict__ spank, u16* __restrict__ spanv)
{
  const int c = 1 << LVL;
  const int n = T_ >> LVL;
  const int JW = c >> 2;
  int bid = blockIdx.x;
  int h = bid & (H_-1);
  int rest = bid >> 4;
  int m = rest % n;
  int b = rest / n;
  int tid = threadIdx.x, lane = tid & 63, w = tid >> 6;
  size_t base = ((size_t)(b*T_ + m*c)*H_ + h)*DHD;
  const int str = H_*DHD;

  __shared__ float sq_sh[DHD];
  __shared__ float red[4][DHD];
  __shared__ float e_sh[1024];
  __shared__ float mred[4], sred[4];

  float mq = -1e30f, mk = -1e30f;
  int j0 = w*JW, j1 = j0 + JW;
  for (int j = j0; j < j1; ++j) {
    mq = fmaxf(mq, b2f(q[base + (size_t)j*str + lane]));
    mk = fmaxf(mk, b2f(k[base + (size_t)j*str + lane]));
  }
  red[w][lane] = mq;
  __syncthreads();
  if (w == 0)
    sq_sh[lane] = fmaxf(fmaxf(red[0][lane], red[1][lane]),
                        fmaxf(red[2][lane], red[3][lane]));
  __syncthreads();
  red[w][lane] = mk;
  __syncthreads();
  mk = fmaxf(fmaxf(red[0][lane], red[1][lane]), fmaxf(red[2][lane], red[3][lane]));

  float lmax = -1e30f;
  for (int j = tid; j < c; j += 256) {
    const u16* kr = k + base + (size_t)j*str;
    float dot = 0.f;
    #pragma unroll
    for (int d0 = 0; d0 < 64; d0 += 8) {
      bf16x8 kv = *(const bf16x8*)(kr + d0);
      #pragma unroll
      for (int e = 0; e < 8; ++e)
        dot += sq_sh[d0+e] * b2f(((const u16*)&kv)[e]);
    }
    e_sh[j] = dot;
    lmax = fmaxf(lmax, dot);
  }
  #pragma unroll
  for (int o=32;o>0;o>>=1) lmax = fmaxf(lmax, __shfl_xor(lmax,o));
  if (lane==0) mred[w] = lmax;
  __syncthreads();
  float M = fmaxf(fmaxf(mred[0],mred[1]),fmaxf(mred[2],mred[3]));
  float spart = 0.f;
  for (int j = tid; j < c; j += 256) {
    float e = __expf(e_sh[j] - M);
    e_sh[j] = e;
    spart += e;
  }
  #pragma unroll
  for (int o=32;o>0;o>>=1) spart += __shfl_xor(spart,o);
  if (lane==0) sred[w] = spart;
  __syncthreads();
  float S = sred[0]+sred[1]+sred[2]+sred[3];

  float acc = 0.f;
  for (int j = j0; j < j1; ++j)
    acc += e_sh[j] * b2f(v[base + (size_t)j*str + lane]);
  red[w][lane] = acc;
  __syncthreads();
  if (w == 0) {
    float a = red[0][lane]+red[1][lane]+red[2][lane]+red[3][lane];
    size_t so = ((size_t)(b*n + m)*H_ + h)*DHD + lane;
    spanv[so] = f2b(a / S);
    spank[so] = f2b(mk);
  }
}

// ---------------- merge: 2 threads per (b,t,h), 32 dims each ----------------
__device__ __forceinline__ float dot32(const u16* __restrict__ row, const float* __restrict__ qd){
  float s = 0.f;
  #pragma unroll
  for (int j=0;j<4;j++){
    uint4 kv = *(const uint4*)(row + j*8);
    s += qd[j*8+0]*bl(kv.x) + qd[j*8+1]*bh(kv.x);
    s += qd[j*8+2]*bl(kv.y) + qd[j*8+3]*bh(kv.y);
    s += qd[j*8+4]*bl(kv.z) + qd[j*8+5]*bh(kv.z);
    s += qd[j*8+6]*bl(kv.w) + qd[j*8+7]*bh(kv.w);
  }
  return s;
}
__device__ __forceinline__ void axpy32(float w, const u16* __restrict__ row, float* __restrict__ acc){
  #pragma unroll
  for (int j=0;j<4;j++){
    uint4 kv = *(const uint4*)(row + j*8);
    acc[j*8+0] += w*bl(kv.x); acc[j*8+1] += w*bh(kv.x);
    acc[j*8+2] += w*bl(kv.y); acc[j*8+3] += w*bh(kv.y);
    acc[j*8+4] += w*bl(kv.z); acc[j*8+5] += w*bh(kv.z);
    acc[j*8+6] += w*bl(kv.w); acc[j*8+7] += w*bh(kv.w);
  }
}

__global__ __launch_bounds__(256) void merge_kernel(
    const u16* __restrict__ q, const u16* __restrict__ k, const u16* __restrict__ v,
    const u16* __restrict__ spank, const u16* __restrict__ spanv,
    u16* __restrict__ merged)
{
  int tid  = threadIdx.x;
  int eidx = blockIdx.x*128 + (tid>>1);     // (b*2048+t)*16+h
  int half = tid & 1;
  int h = eidx & 15;
  int t = (eidx >> 4) & (T_-1);
  unsigned qrow = (unsigned)eidx*64u + (unsigned)half*32u;
  int b = eidx >> 15;

  float qd[32];
  {
    const u16* qr = q + qrow;
    #pragma unroll
    for (int j=0;j<4;j++){
      uint4 kv = *(const uint4*)(qr + j*8);
      qd[j*8+0]=bl(kv.x); qd[j*8+1]=bh(kv.x);
      qd[j*8+2]=bl(kv.y); qd[j*8+3]=bh(kv.y);
      qd[j*8+4]=bl(kv.z); qd[j*8+5]=bh(kv.z);
      qd[j*8+6]=bl(kv.w); qd[j*8+7]=bh(kv.w);
    }
  }

  float lg[12];
  unsigned off[11];
  unsigned msk = 0;
  { float p = dot32(k + qrow, qd); lg[0] = p + __shfl_xor(p, 1); }

  #pragma unroll
  for (int l=0; l<LOGL; l++){
    const int c = 1<<l;
    bool mk = false; unsigned o = 0;
    if (t >= c) {
      int m = (t - c) >> l;
      if ((m & 1) == 0) {
        mk = true;
        if (l == 0) {
          o = qrow - 1024u;                          // row (b,t-1,h)
        } else {
          const int n = T_>>l;
          unsigned choff = 8u*(2048u - (4096u>>l));
          o = ((choff + (unsigned)(b*n + m))*16u + (unsigned)h)*64u + (unsigned)half*32u;
        }
      }
    }
    float L = -1e30f;
    if (mk) {
      const u16* row = (l==0) ? (k + o) : (spank + o);
      float p = dot32(row, qd);
      L = p + __shfl_xor(p, 1);
    }
    lg[l+1] = L;
    off[l] = o;
    if (mk) msk |= (1u<<l);
  }

  float M = lg[0];
  #pragma unroll
  for (int i=1;i<12;i++) M = fmaxf(M, lg[i]);
  float w[12]; float s = 0.f;
  #pragma unroll
  for (int i=0;i<12;i++){ w[i] = __expf(lg[i]-M); s += w[i]; }

  float acc[32];
  #pragma unroll
  for (int d=0;d<32;d++) acc[d] = 0.f;
  axpy32(w[0], v + qrow, acc);
  #pragma unroll
  for (int l=0; l<LOGL; l++){
    if (msk & (1u<<l)) {
      const u16* row = (l==0) ? (v + off[l]) : (spanv + off[l]);
      axpy32(w[l+1], row, acc);
    }
  }

  float inv = 1.f/s;
  u16 ob[32];
  #pragma unroll
  for (int d=0;d<32;d++) ob[d] = f2b(acc[d]*inv);
  u16* orow = merged + qrow;
  *(uint4*)(orow)      = *(uint4*)(ob);
  *(uint4*)(orow + 8)  = *(uint4*)(ob+8);
  *(uint4*)(orow + 16) = *(uint4*)(ob+16);
  *(uint4*)(orow + 24) = *(uint4*)(ob+24);
}

// ---------------- launch ----------------
extern "C" void kernel_launch(void* const* d_in, const int* in_sizes, int n_in,
                              void* d_out, int out_size, void* d_ws, size_t ws_size,
                              hipStream_t stream) {
  (void)in_sizes; (void)n_in; (void)out_size; (void)ws_size;
  const float* x  = (const float*)d_in[0];
  const float* Wq = (const float*)d_in[1];
  const float* Wk = (const float*)d_in[2];
  const float* Wv = (const float*)d_in[3];
  const float* Wo = (const float*)d_in[4];
  float* out = (float*)d_out;

  uint8_t* w = (uint8_t*)d_ws;
  u16* xb     = (u16*)(w);                   // 32 MB (reused as merged)
  u16* qb     = (u16*)(w + 33554432ull);     // 32 MB
  u16* kb     = (u16*)(w + 67108864ull);     // 32 MB
  u16* vb     = (u16*)(w + 100663296ull);    // 32 MB
  u16* spank  = (u16*)(w + 134217728ull);    // 32 MB
  u16* spanv  = (u16*)(w + 167772160ull);    // 32 MB
  u16* wqkvT  = (u16*)(w + 201326592ull);    // 6 MB  [3072][1024] B^T
  u16* woT    = (u16*)(w + 207618048ull);    // 2 MB  [1024][1024] B^T

  convert_x_kernel<<<8192, 256, 0, stream>>>(x, xb);
  wtrans_kernel<<<dim3(16,16,4), 256, 0, stream>>>(Wq, Wk, Wv, Wo, wqkvT, woT);

  gemm_kernel<1><<<dim3(24,128), 256, 0, stream>>>(xb, wqkvT, nullptr, qb, kb, vb,
                                                   16384, 3072, 1024);

  #define SPAN(L) do { \
    size_t choff = (size_t)(B_*(2048 - (4096>>(L)))); \
    span_kernel<L><<<(65536>>(L)), 256, 0, stream>>>(qb, kb, vb, \
        spank + choff*1024, spanv + choff*1024); \
  } while(0)
  #define SPANL(L) do { \
    size_t choff = (size_t)(B_*(2048 - (4096>>(L)))); \
    span_large_kernel<L><<<(262144>>(L)), 256, 0, stream>>>(qb, kb, vb, \
        spank + choff*1024, spanv + choff*1024); \
  } while(0)
  SPAN(1); SPAN(2); SPAN(3); SPAN(4); SPAN(5);
  SPANL(6); SPANL(7); SPANL(8); SPANL(9); SPANL(10);
  #undef SPAN
  #undef SPANL

  merge_kernel<<<2048, 256, 0, stream>>>(qb, kb, vb, spank, spanv, xb /*merged*/);

  gemm_kernel<0><<<dim3(8,128), 256, 0, stream>>>(xb, woT, out, nullptr, nullptr, nullptr,
                                                  16384, 1024, 1024);
}